// Round 3
// baseline (435.077 us; speedup 1.0000x reference)
//
#include <hip/hip_runtime.h>
#include <hip/hip_bf16.h>

// ---------------------------------------------------------------------------
// GAT 2-layer forward on MI355X (gfx950).
// R9b: resubmit of R9 (container infra failure, no signal).
// R9: XCD column-striped aggregation — h stored column-sliced [HC/32][N][32];
//     blocks with bid%8==s gather only slice s (3.2/1.6 MB -> L2-resident on
//     that XCD). csr_src read non-temporally (don't evict the stripe).
//     Persistent grid: 2048 blocks (32 waves/CU, one shot). gemm C-stores
//     write the sliced layout; gemm2 A-stage reads sliced o1 (BK=32 = one
//     slice chunk). gemm1 head-pairs swizzled 8 apart in bid -> same XCD ->
//     A-tile read from HBM once instead of twice.
// R8: grouped 16B gather (neutral — proved gather is cache-delivery-bound).
// R7: rank-trick atomic-free CSR scatter fused into gemm1 as dedicated blocks.
// fp16 intermediates, MFMA f16 GEMMs + fused att-logit epilogue, softmax
// shift-invariance (no max pass), end-normalization (no denom pass).
// ---------------------------------------------------------------------------

typedef _Float16 half8v __attribute__((ext_vector_type(8)));
typedef _Float16 half4v __attribute__((ext_vector_type(4)));
typedef _Float16 half2v __attribute__((ext_vector_type(2)));
typedef float f32x4 __attribute__((ext_vector_type(4)));

// --- MFMA GEMM + fused attention logits (+ block-specialized scatter) ------
// GEMM blocks: C[M, H*128](f16, SLICED [NCOL/32][M][32]) = A[M,K] @ B^T.
// A: float path = row-major x; _Float16 path = SLICED layout (o1).
// Scatter blocks (bid >= GB*H): atomic-free CSR scatter via precomputed rank.

template <typename TA, int H, bool SCATTER>
__global__ __launch_bounds__(256) void gemm_att_kernel(
    const TA* __restrict__ A,
    const float* __restrict__ B,     // [H*128, K] row-major fp32 weights
    _Float16* __restrict__ C,        // SLICED [NCOL/32][M][32] fp16 out
    const float* __restrict__ att_s, // [H*128]
    const float* __restrict__ att_d, // [H*128]
    float* __restrict__ a_s,         // [M*H]
    float* __restrict__ a_d,         // [M*H]
    int M, int K, int GB,            // GB = GEMM blocks per head
    const int* __restrict__ esrc, const int* __restrict__ edst,
    const int* __restrict__ rank, const int* __restrict__ csr_off,
    int* __restrict__ csr_src, int E, int nScatBlk)
{
    constexpr int BM = 128, BK = 32, LDA = 40;   // 40 f16 = 80 B = 5*16 B
    constexpr int NCOL = H * 128;
    __shared__ _Float16 Ah[BM * LDA];
    __shared__ _Float16 Bh[BM * LDA];
    __shared__ float red[2][2][64][2];           // [wm][wn][row][s|d]

    const int tid = threadIdx.x;
    const int bid = blockIdx.x;

    if constexpr (SCATTER) {
        if (bid >= GB * H) {
            const int sbid = bid - GB * H;
            const int nq = (E + 3) >> 2;
            for (int q = sbid * 256 + tid; q < nq; q += nScatBlk * 256) {
                const int e4 = q * 4;
                if (e4 + 3 < E) {
                    const int4 sv = *reinterpret_cast<const int4*>(esrc + e4);
                    const int4 dv = *reinterpret_cast<const int4*>(edst + e4);
                    const int4 rv = *reinterpret_cast<const int4*>(rank + e4);
                    csr_src[csr_off[dv.x] + 1 + rv.x] = sv.x;
                    csr_src[csr_off[dv.y] + 1 + rv.y] = sv.y;
                    csr_src[csr_off[dv.z] + 1 + rv.z] = sv.z;
                    csr_src[csr_off[dv.w] + 1 + rv.w] = sv.w;
                } else {
                    for (int k = e4; k < E; ++k)
                        csr_src[csr_off[edst[k]] + 1 + rank[k]] = esrc[k];
                }
            }
            return;
        }
    }

    // head-pair swizzle: (m,0) and (m,1) land 8 bids apart -> same XCD,
    // dispatched in the same window -> A-tile read from HBM once.
    int m0, by;
    if (H == 2 && (GB & 7) == 0) {
        const int cc = bid >> 4, jj = bid & 15;
        m0 = ((cc << 3) + (jj & 7)) * BM;
        by = jj >> 3;
    } else {
        m0 = (bid % GB) * BM;
        by = bid / GB;
    }
    const int n0 = by * 128;
    const int w  = tid >> 6;
    const int l  = tid & 63;
    const int wm = (w >> 1) * 64;
    const int wn = (w & 1) * 64;
    const int lr = l & 15;
    const int lq = l >> 4;

    f32x4 acc[4][4] = {};

    for (int k0 = 0; k0 < K; k0 += BK) {
        if constexpr (__is_same(TA, float)) {
#pragma unroll
            for (int it = 0; it < 4; ++it) {
                const int row = (tid >> 3) + it * 32;
                const int gm  = min(m0 + row, M - 1);
                const int c4  = (tid & 7) * 4;
                float4 v = *reinterpret_cast<const float4*>(A + (long)gm * K + k0 + c4);
                half4v o = { (_Float16)v.x, (_Float16)v.y, (_Float16)v.z, (_Float16)v.w };
                *reinterpret_cast<half4v*>(&Ah[row * LDA + c4]) = o;
            }
        } else {
            // sliced A: [K/32][M][32]; BK==32 -> one chunk per k-step
#pragma unroll
            for (int it = 0; it < 2; ++it) {
                const int row = (tid >> 2) + it * 64;
                const int gm  = min(m0 + row, M - 1);
                const int c8  = (tid & 3) * 8;
                const _Float16* src = (const _Float16*)A +
                    ((size_t)(k0 >> 5) * M + gm) * 32 + c8;
                float4 v = *reinterpret_cast<const float4*>(src);
                *reinterpret_cast<float4*>(&Ah[row * LDA + c8]) = v;
            }
        }
#pragma unroll
        for (int it = 0; it < 4; ++it) {
            const int row = (tid >> 3) + it * 32;
            const int c4  = (tid & 7) * 4;
            float4 v = *reinterpret_cast<const float4*>(B + (long)(n0 + row) * K + k0 + c4);
            half4v o = { (_Float16)v.x, (_Float16)v.y, (_Float16)v.z, (_Float16)v.w };
            *reinterpret_cast<half4v*>(&Bh[row * LDA + c4]) = o;
        }
        __syncthreads();

        half8v af[4], bf[4];
#pragma unroll
        for (int i = 0; i < 4; ++i)
            af[i] = *reinterpret_cast<const half8v*>(&Ah[(wm + i * 16 + lr) * LDA + lq * 8]);
#pragma unroll
        for (int j = 0; j < 4; ++j)
            bf[j] = *reinterpret_cast<const half8v*>(&Bh[(wn + j * 16 + lr) * LDA + lq * 8]);
#pragma unroll
        for (int i = 0; i < 4; ++i)
#pragma unroll
            for (int j = 0; j < 4; ++j)
                acc[i][j] = __builtin_amdgcn_mfma_f32_16x16x32_f16(af[i], bf[j], acc[i][j], 0, 0, 0);
        __syncthreads();
    }

    // ---- store C (sliced [NCOL/32][M][32]) ----
#pragma unroll
    for (int i = 0; i < 4; ++i) {
        const int gm_base = m0 + wm + i * 16 + lq * 4;
#pragma unroll
        for (int r = 0; r < 4; ++r) {
            const int gm = gm_base + r;
            if (gm < M) {
#pragma unroll
                for (int j = 0; j < 4; ++j) {
                    const int col = n0 + wn + j * 16 + lr;
                    C[((size_t)(col >> 5) * M + gm) * 32 + (col & 31)] =
                        (_Float16)acc[i][j][r];
                }
            }
        }
    }

    // ---- fused attention logits ----
    float asv[4], adv[4];
#pragma unroll
    for (int j = 0; j < 4; ++j) {
        asv[j] = att_s[n0 + wn + j * 16 + lr];
        adv[j] = att_d[n0 + wn + j * 16 + lr];
    }
    float ps[4][4] = {}, pd[4][4] = {};
#pragma unroll
    for (int i = 0; i < 4; ++i)
#pragma unroll
        for (int j = 0; j < 4; ++j)
#pragma unroll
            for (int r = 0; r < 4; ++r) {
                ps[i][r] += acc[i][j][r] * asv[j];
                pd[i][r] += acc[i][j][r] * adv[j];
            }
#pragma unroll
    for (int o = 1; o < 16; o <<= 1)
#pragma unroll
        for (int i = 0; i < 4; ++i)
#pragma unroll
            for (int r = 0; r < 4; ++r) {
                ps[i][r] += __shfl_xor(ps[i][r], o, 64);
                pd[i][r] += __shfl_xor(pd[i][r], o, 64);
            }
    if (lr == 0) {
#pragma unroll
        for (int i = 0; i < 4; ++i)
#pragma unroll
            for (int r = 0; r < 4; ++r) {
                const int row = i * 16 + lq * 4 + r;
                red[wm >> 6][wn >> 6][row][0] = ps[i][r];
                red[wm >> 6][wn >> 6][row][1] = pd[i][r];
            }
    }
    __syncthreads();
    if (wn == 0) {                       // waves 0 and 2 cover wm = 0, 64
        const int row = l;
        const int gm = m0 + wm + row;
        if (gm < M) {
            const int wi = wm >> 6;
            a_s[(long)gm * H + by] = red[wi][0][row][0] + red[wi][1][row][0];
            a_d[(long)gm * H + by] = red[wi][0][row][1] + red[wi][1][row][1];
        }
    }
}

// --- CSR build --------------------------------------------------------------

__global__ void count_kernel(const int* __restrict__ dst, int* __restrict__ deg,
                             int* __restrict__ rank, int E)
{
    const int tid = blockIdx.x * blockDim.x + threadIdx.x;
    const int e4 = tid * 4;
    if (e4 + 3 < E) {
        const int4 d = *reinterpret_cast<const int4*>(dst + e4);
        int4 r;
        r.x = atomicAdd(&deg[d.x], 1);
        r.y = atomicAdd(&deg[d.y], 1);
        r.z = atomicAdd(&deg[d.z], 1);
        r.w = atomicAdd(&deg[d.w], 1);
        *reinterpret_cast<int4*>(rank + e4) = r;
    } else if (e4 < E) {
        for (int k = e4; k < E; ++k) rank[k] = atomicAdd(&deg[dst[k]], 1);
    }
}

__global__ __launch_bounds__(256) void block_scan_kernel(
    const int* __restrict__ deg, int* __restrict__ pre, int* __restrict__ blk, int n)
{
    __shared__ int s[256];
    const int t = threadIdx.x;
    const int base = blockIdx.x * 1024 + t * 4;
    int4 d = make_int4(-1, -1, -1, -1);   // +1 -> 0 contribution OOB
    if (base + 3 < n) d = *reinterpret_cast<const int4*>(deg + base);
    else {
        if (base + 0 < n) d.x = deg[base + 0];
        if (base + 1 < n) d.y = deg[base + 1];
        if (base + 2 < n) d.z = deg[base + 2];
        if (base + 3 < n) d.w = deg[base + 3];
    }
    const int v0 = d.x + 1, v1 = d.y + 1, v2 = d.z + 1, v3 = d.w + 1;
    s[t] = v0 + v1 + v2 + v3;
    __syncthreads();
#pragma unroll
    for (int o = 1; o < 256; o <<= 1) {
        int val = 0;
        if (t >= o) val = s[t - o];
        __syncthreads();
        s[t] += val;
        __syncthreads();
    }
    int run = (t == 0) ? 0 : s[t - 1];
    int4 o4;
    o4.x = run; run += v0;
    o4.y = run; run += v1;
    o4.z = run; run += v2;
    o4.w = run; run += v3;
    if (base + 3 < n) *reinterpret_cast<int4*>(pre + base) = o4;
    else {
        if (base + 0 < n) pre[base + 0] = o4.x;
        if (base + 1 < n) pre[base + 1] = o4.y;
        if (base + 2 < n) pre[base + 2] = o4.z;
        if (base + 3 < n) pre[base + 3] = o4.w;
    }
    if (t == 255) blk[blockIdx.x] = s[255];
}

__global__ __launch_bounds__(256) void finalize_scan_kernel(
    const int* __restrict__ pre, const int* __restrict__ blk,
    int* __restrict__ off, int* __restrict__ csr_src, int n, int nvb)
{
    __shared__ int s_add;
    const int vb = blockIdx.x;
    const int t  = threadIdx.x;
    if (t < 64) {
        int v = (t < vb) ? blk[t] : 0;    // nvb <= 64
#pragma unroll
        for (int o = 32; o > 0; o >>= 1) v += __shfl_xor(v, o, 64);
        if (t == 0) s_add = v;
    }
    __syncthreads();
    const int add = s_add;
    const int base = vb * 1024 + t * 4;
    if (base + 3 < n) {
        int4 p = *reinterpret_cast<const int4*>(pre + base);
        p.x += add; p.y += add; p.z += add; p.w += add;
        *reinterpret_cast<int4*>(off + base) = p;
        csr_src[p.x] = base + 0;
        csr_src[p.y] = base + 1;
        csr_src[p.z] = base + 2;
        csr_src[p.w] = base + 3;
    } else {
#pragma unroll
        for (int k = 0; k < 4; ++k)
            if (base + k < n) {
                const int v = pre[base + k] + add;
                off[base + k] = v;
                csr_src[v] = base + k;
            }
    }
    if (vb == nvb - 1 && t == 0) off[n] = add + blk[vb];
}

// --- XCD-striped pull aggregation ------------------------------------------
// h is SLICED [HC/32][N][32]. Block's slice = (bid%8)%NS -> XCD bid%8 only
// touches a 3.2/1.6 MB contiguous stripe => L2-resident gathers.
// Per wave: one dst at a time (4 dsts/block in flight), 64-edge LDS tiles of
// {src, exp-weight}, groups of 8 lanes gather 8 edges/iter (8B half4 each =
// one 64B line per edge). Cross-group shfl_xor reduce; slice-local wsum is
// bitwise-identical across slices. No block barrier (wave-private LDS rows).

template <int H, int C, bool RELU, typename TOUT>
__global__ __launch_bounds__(256) void aggregate_kernel(
    const int* __restrict__ csr_off,
    const int* __restrict__ csr_src,
    const _Float16* __restrict__ h,  // sliced [HC/32][N][32] fp16
    const float* __restrict__ a_s,   // [N,H]
    const float* __restrict__ a_d,   // [N,H]
    const float* __restrict__ bias,  // [HC]
    TOUT* __restrict__ out,          // f16: sliced [HC/32][N][32]; f32: [N,HC]
    int N, int G8)                   // G8 = gridDim.x / 8
{
    constexpr int HC  = H * C;
    constexpr int NS  = HC / 32;     // slices: 8 (L1), 4 (L2)
    constexpr int REP = 8 / NS;      // XCD groups per slice
    const int w  = threadIdx.x >> 6;
    const int l  = threadIdx.x & 63;
    const int b8 = blockIdx.x & 7;
    const int slice = b8 % NS;
    const int hh = (slice * 32) / C; // head of this slice
    const int g2 = (blockIdx.x >> 3) * REP + b8 / NS;
    const int dstride = G8 * REP * 4;
    const int g  = l >> 3;           // edge group 0..7
    const int cl = (l & 7) * 4;      // col within slice

    __shared__ float2 s_sw[4][64];   // [wave][edge] = {src, w}
    const _Float16* __restrict__ hs = h + (size_t)slice * N * 32;

    for (int d = g2 * 4 + w; d < N; d += dstride) {
        const int beg = csr_off[d];
        const int end = csr_off[d + 1];
        const float ad = a_d[d * H + hh];
        float acc[4] = {};
        float wsum = 0.f;

        for (int base = beg; base < end; base += 64) {
            const int len = min(64, end - base);
            float2 sw;
            if (l < len) {
                const int s = __builtin_nontemporal_load(csr_src + base + l);
                float lg = a_s[s * H + hh] + ad;
                lg = lg > 0.f ? lg : 0.2f * lg;
                sw = make_float2(__int_as_float(s), __expf(lg));
            } else {                 // padding: weight 0, safe src = d
                sw = make_float2(__int_as_float(d), 0.f);
            }
            s_sw[w][l] = sw;
            __builtin_amdgcn_wave_barrier();
            const int iters = (len + 7) >> 3;
            for (int jj = 0; jj < iters; ++jj) {
                const float2 e = s_sw[w][jj * 8 + g];
                const int    s = __float_as_int(e.x);
                const float wt = e.y;
                const half4v hv = *reinterpret_cast<const half4v*>(
                    hs + (size_t)s * 32 + cl);
                acc[0] += wt * (float)hv.x;
                acc[1] += wt * (float)hv.y;
                acc[2] += wt * (float)hv.z;
                acc[3] += wt * (float)hv.w;
                wsum += wt;
            }
            __builtin_amdgcn_wave_barrier();
        }

        // cross-group reduce (groups cover disjoint edges, same columns)
#pragma unroll
        for (int o = 8; o < 64; o <<= 1) {
#pragma unroll
            for (int k = 0; k < 4; ++k) acc[k] += __shfl_xor(acc[k], o, 64);
            wsum += __shfl_xor(wsum, o, 64);
        }

        if (g == 0) {
            const float inv = 1.f / wsum;
            float r[4];
#pragma unroll
            for (int k = 0; k < 4; ++k) {
                r[k] = acc[k] * inv + bias[slice * 32 + cl + k];
                if (RELU) r[k] = r[k] > 0.f ? r[k] : 0.f;
            }
            if constexpr (__is_same(TOUT, _Float16)) {
                half4v ov = { (_Float16)r[0], (_Float16)r[1],
                              (_Float16)r[2], (_Float16)r[3] };
                *reinterpret_cast<half4v*>(
                    out + ((size_t)slice * N + d) * 32 + cl) = ov;
            } else {
                f32x4 ov = { r[0], r[1], r[2], r[3] };
                *reinterpret_cast<f32x4*>(
                    out + (size_t)d * HC + slice * 32 + cl) = ov;
            }
        }
    }
}

// ---------------------------------------------------------------------------

extern "C" void kernel_launch(void* const* d_in, const int* in_sizes, int n_in,
                              void* d_out, int out_size, void* d_ws, size_t ws_size,
                              hipStream_t stream)
{
    const float* x    = (const float*)d_in[0];
    const int*   eidx = (const int*)d_in[1];
    const float* W1   = (const float*)d_in[2];
    const float* as1  = (const float*)d_in[3];
    const float* ad1  = (const float*)d_in[4];
    const float* b1   = (const float*)d_in[5];
    const float* W2   = (const float*)d_in[6];
    const float* as2  = (const float*)d_in[7];
    const float* ad2  = (const float*)d_in[8];
    const float* b2   = (const float*)d_in[9];
    float* out = (float*)d_out;

    const int IN_FEATS = 256;
    const int N = in_sizes[0] / IN_FEATS;    // 50000
    const int E = in_sizes[1] / 2;           // 800000

    const int* esrc = eidx;
    const int* edst = eidx + E;

    size_t off = 0;
    auto alloc = [&](size_t bytes) -> void* {
        void* p = (char*)d_ws + off;
        off += (bytes + 255) & ~(size_t)255;
        return p;
    };
    _Float16* h1h   = (_Float16*)alloc((size_t)N * 256 * 2);   // sliced [8][N][32]
    _Float16* o1h   = (_Float16*)alloc((size_t)N * 256 * 2);   // sliced [8][N][32]
    _Float16* h2h   = (_Float16*)alloc((size_t)N * 128 * 2);   // sliced [4][N][32]
    float* a1s      = (float*)alloc((size_t)N * 2 * 4);
    float* a1d      = (float*)alloc((size_t)N * 2 * 4);
    float* a2s      = (float*)alloc((size_t)N * 4);
    float* a2d      = (float*)alloc((size_t)N * 4);
    int*   deg      = (int*)alloc((size_t)N * 4);
    int*   pre      = (int*)alloc((size_t)N * 4);
    int*   rank     = (int*)alloc((size_t)E * 4);
    int*   csr_off  = (int*)alloc((size_t)(N + 1) * 4);
    int*   csr_src  = (int*)alloc((size_t)(E + N) * 4);
    int*   blk      = (int*)alloc(64 * 4);

    const int nvb = (N + 1023) / 1024;    // 49 <= 64

    // --- CSR offsets + ranks (scatter itself fused into gemm1) ---
    hipMemsetAsync(deg, 0, (size_t)N * 4, stream);
    count_kernel<<<((E + 3) / 4 + 255) / 256, 256, 0, stream>>>(edst, deg, rank, E);
    block_scan_kernel<<<nvb, 256, 0, stream>>>(deg, pre, blk, N);
    finalize_scan_kernel<<<nvb, 256, 0, stream>>>(pre, blk, csr_off, csr_src, N, nvb);

    // --- layer 1: GEMM(784 blocks, head-paired) + scatter blocks(192) ---
    {
        const int GB = (N + 127) / 128;      // 392 (multiple of 8)
        const int nScat = 192;               // 784 + 192 = 976 co-resident
        gemm_att_kernel<float, 2, true><<<GB * 2 + nScat, 256, 0, stream>>>(
            x, W1, h1h, as1, ad1, a1s, a1d, N, 256, GB,
            esrc, edst, rank, csr_off, csr_src, E, nScat);
    }
    {
        const int G8 = 256;                  // 2048 blocks = 32 waves/CU
        aggregate_kernel<2, 128, true, _Float16><<<G8 * 8, 256, 0, stream>>>(
            csr_off, csr_src, h1h, a1s, a1d, b1, o1h, N, G8);
    }

    // --- layer 2: GEMM + att logits, then aggregate ---
    {
        const int GB = (N + 127) / 128;
        gemm_att_kernel<_Float16, 1, false><<<GB, 256, 0, stream>>>(
            o1h, W2, h2h, as2, ad2, a2s, a2d, N, 256, GB,
            nullptr, nullptr, nullptr, nullptr, nullptr, 0, 0);
    }
    {
        const int G8 = 256;
        aggregate_kernel<1, 128, false, float><<<G8 * 8, 256, 0, stream>>>(
            csr_off, csr_src, h2h, a2s, a2d, b2, out, N, G8);
    }
}